// Round 17
// baseline (1512.661 us; speedup 1.0000x reference)
//
#include <hip/hip_runtime.h>

typedef short s16x8 __attribute__((ext_vector_type(8)));
typedef float f32x4 __attribute__((ext_vector_type(4)));
typedef unsigned short u16;
typedef unsigned int u32;

__device__ __forceinline__ float bf2f(u16 u) {
  union { unsigned int i; float f; } v; v.i = ((unsigned int)u) << 16; return v.f;
}
__device__ __forceinline__ u16 f2bf(float f) {
  union { float f; unsigned int i; } v; v.f = f;
  unsigned int r = v.i + 0x7fffu + ((v.i >> 16) & 1u);
  return (u16)(r >> 16);
}
__device__ __forceinline__ float bflo(u32 x) {
  union { unsigned int i; float f; } v; v.i = x << 16; return v.f;
}
__device__ __forceinline__ float bfhi(u32 x) {
  union { unsigned int i; float f; } v; v.i = x & 0xffff0000u; return v.f;
}

// async global->LDS, 16B per lane. LDS dest must be wave-uniform; HW adds lane*16.
__device__ __forceinline__ void gload16(const u16* g, u16* l) {
  __builtin_amdgcn_global_load_lds(
      (const __attribute__((address_space(1))) u32*)g,
      (__attribute__((address_space(3))) u32*)l, 16, 0, 0);
}

// -------- weight transpose + cast (+ optional gamma fold on K axis) ----------
// in[K][N] f32 -> out[N][K] bf16; out[n][k] = in[k][n] * (gamma ? gamma[k] : 1)
template<int KDIM, int NDIM>
__launch_bounds__(256)
__global__ void wprep(const float* __restrict__ in, u16* __restrict__ out,
                      const float* __restrict__ gamma) {
  __shared__ float t[64][65];
  const int tid = threadIdx.x;
  const int nb = NDIM / 64;
  const int tk0 = (blockIdx.x / nb) * 64;
  const int tn0 = (blockIdx.x % nb) * 64;
#pragma unroll
  for (int i = 0; i < 16; i++) {
    int idx = i * 256 + tid;
    int r = idx >> 6, c = idx & 63;
    float g = gamma ? gamma[tk0 + r] : 1.0f;
    t[r][c] = in[(long)(tk0 + r) * NDIM + (tn0 + c)] * g;
  }
  __syncthreads();
#pragma unroll
  for (int i = 0; i < 16; i++) {
    int idx = i * 256 + tid;
    int nn = idx >> 6, kk = idx & 63;
    out[(long)(tn0 + nn) * KDIM + (tk0 + kk)] = f2bf(t[kk][nn]);
  }
}

// ---------------- rmsnorm (f32 src) + cast to bf16 --------------------------
__launch_bounds__(256)
__global__ void rmsnorm_f32(const float* __restrict__ x, const float* __restrict__ w,
                            u16* __restrict__ out) {
  const long row = (long)blockIdx.x * 4 + (threadIdx.x >> 6);
  const int lane = threadIdx.x & 63;
  const float* xr = x + row * 512 + lane * 8;
  float4 v0 = *(const float4*)xr;
  float4 v1 = *(const float4*)(xr + 4);
  float ss = v0.x*v0.x + v0.y*v0.y + v0.z*v0.z + v0.w*v0.w
           + v1.x*v1.x + v1.y*v1.y + v1.z*v1.z + v1.w*v1.w;
#pragma unroll
  for (int o = 1; o < 64; o <<= 1) ss += __shfl_xor(ss, o);
  float sc = rsqrtf(ss * (1.0f / 512.0f) + 1e-6f);
  const float* wp = w + lane * 8;
  float4 w0 = *(const float4*)wp;
  float4 w1 = *(const float4*)(wp + 4);
  union { u16 u[8]; uint4 v; } o;
  o.u[0] = f2bf(v0.x * sc * w0.x);
  o.u[1] = f2bf(v0.y * sc * w0.y);
  o.u[2] = f2bf(v0.z * sc * w0.z);
  o.u[3] = f2bf(v0.w * sc * w0.w);
  o.u[4] = f2bf(v1.x * sc * w1.x);
  o.u[5] = f2bf(v1.y * sc * w1.y);
  o.u[6] = f2bf(v1.z * sc * w1.z);
  o.u[7] = f2bf(v1.w * sc * w1.w);
  *(uint4*)(out + row * 512 + lane * 8) = o.v;
}

// ---------------- row scale only (bf16 src): s[row] = rsqrt(mean(x^2)+eps) ---
__launch_bounds__(256)
__global__ void rowscale_bf16(const u16* __restrict__ x, float* __restrict__ s) {
  const long row = (long)blockIdx.x * 4 + (threadIdx.x >> 6);
  const int lane = threadIdx.x & 63;
  uint4 u = *(const uint4*)(x + row * 512 + lane * 8);
  const u16* us = (const u16*)&u;
  float ss = 0.f;
#pragma unroll
  for (int j = 0; j < 8; j++) { float f = bf2f(us[j]); ss += f * f; }
#pragma unroll
  for (int o = 1; o < 64; o <<= 1) ss += __shfl_xor(ss, o);
  if (lane == 0) s[row] = rsqrtf(ss * (1.0f / 512.0f) + 1e-6f);
}

// ---- 128x128 dbuf counted-vmcnt GEMM + LDS-staged coalesced epilogue --------
// rs (optional): per-row scale applied to acc before the epilogue nonlinearity
// (rmsnorm row factor; gamma pre-folded into Bt).
enum { EPI_BF16 = 0, EPI_PHI = 1, EPI_RESX = 2, EPI_RESH = 3, EPI_SILUMUL = 4,
       EPI_OUTF = 5, EPI_QKV = 6, EPI_KV = 7 };

template<int KD, int EPI>
__launch_bounds__(256)
__global__ void gemm128(const u16* __restrict__ A, const u16* __restrict__ Bt,
                        void* __restrict__ C0, void* __restrict__ C1,
                        void* __restrict__ C2, const void* __restrict__ aux,
                        int Ns, const float* __restrict__ rs) {
  __shared__ u16 smem[32768];           // 64 KB: As|Bs during loop, Cs in epilogue
  u16* Asm = smem;                      // [2][128][64]
  u16* Bsm = smem + 16384;
  const int tid = threadIdx.x;
  const int lane = tid & 63;
  const int wv = tid >> 6;
  const int gx = gridDim.x;
  int L = blockIdx.y * gx + blockIdx.x;
  const int cpx = (gx * gridDim.y) >> 3;
  L = (L & 7) * cpx + (L >> 3);
  const long m0 = (long)(L / gx) * 128;
  const int nb = L % gx;
  const long n0 = (long)nb * 128;

  const int wr = (wv >> 1) * 64;
  const int wc = (wv & 1) * 64;
  const int fr = lane & 15;
  const int frq = lane >> 4;

  const int r0 = wv * 32 + (lane >> 3);
  const int sg8 = ((lane & 7) ^ ((lane >> 3) & 7)) * 8;
  const u16* Ag = A + (m0 + r0) * KD + sg8;
  const u16* Bg = Bt + (n0 + r0) * KD + sg8;
  u16* Alds = Asm + wv * 2048;
  u16* Blds = Bsm + wv * 2048;

  f32x4 acc[4][4] = {};

  auto STAGE = [&](int b, int kt) {
    const long k0 = (long)kt * 64;
#pragma unroll
    for (int j = 0; j < 4; j++) {
      gload16(Ag + (long)(j * 8) * KD + k0, Alds + b * 8192 + j * 512);
      gload16(Bg + (long)(j * 8) * KD + k0, Blds + b * 8192 + j * 512);
    }
  };
  auto COMPUTE = [&](int b) {
#pragma unroll
    for (int ks = 0; ks < 2; ks++) {
      const int slot = ((ks * 4 + frq) ^ (fr & 7)) * 8;
      s16x8 af[4], bf[4];
#pragma unroll
      for (int i = 0; i < 4; i++)
        af[i] = *(const s16x8*)&Asm[b * 8192 + (wr + i * 16 + fr) * 64 + slot];
#pragma unroll
      for (int j = 0; j < 4; j++)
        bf[j] = *(const s16x8*)&Bsm[b * 8192 + (wc + j * 16 + fr) * 64 + slot];
#pragma unroll
      for (int i = 0; i < 4; i++)
#pragma unroll
        for (int j = 0; j < 4; j++)
          acc[i][j] = __builtin_amdgcn_mfma_f32_16x16x32_bf16(af[i], bf[j], acc[i][j], 0, 0, 0);
    }
  };

  constexpr int NT = KD / 64;
  STAGE(0, 0);
#pragma unroll 1
  for (int t = 0; t < NT; ++t) {
    if (t + 1 < NT) {
      STAGE((t + 1) & 1, t + 1);
      asm volatile("s_waitcnt vmcnt(8)" ::: "memory");
    } else {
      asm volatile("s_waitcnt vmcnt(0)" ::: "memory");
    }
    __builtin_amdgcn_s_barrier();
    COMPUTE(t & 1);
    asm volatile("s_waitcnt lgkmcnt(0)" ::: "memory");
    __builtin_amdgcn_s_barrier();
  }

  // ---- epilogue: stage C-tile bf16 in LDS, then coalesced 16B stores ----
  u16* Cs = smem;
  const int col = lane & 15;
  const int rb = frq * 4;
  const int seg = (EPI == EPI_QKV || EPI == EPI_KV) ? (nb >> 2) : 0;
#pragma unroll
  for (int i = 0; i < 4; i++) {
#pragma unroll
    for (int r = 0; r < 4; r++) {
      const int ml = wr + i * 16 + rb + r;
      const float sc_ = rs ? rs[m0 + ml] : 1.0f;
#pragma unroll
      for (int j = 0; j < 4; j++) {
        const int nl = wc + j * 16 + col;
        float v = acc[i][j][r] * sc_;
        if constexpr (EPI == EPI_PHI) {
          v = v > 0.f ? v + 1.f : __expf(v);
        } else if constexpr (EPI == EPI_QKV) {
          if (seg < 2) v = v > 0.f ? v + 1.f : __expf(v);
        } else if constexpr (EPI == EPI_KV) {
          if (seg == 0) v = v > 0.f ? v + 1.f : __expf(v);
        }
        Cs[ml * 148 + nl] = f2bf(v);
      }
    }
  }
  __syncthreads();

#pragma unroll
  for (int rep = 0; rep < 8; rep++) {
    const int idx = rep * 256 + tid;
    const int row = idx >> 4;
    const int nc = (idx & 15) * 8;      // tile col of this 16B chunk
    const long m = m0 + row;
    uint4 vv = *(const uint4*)&Cs[row * 148 + nc];
    const u16* vp = (const u16*)&vv;
    if constexpr (EPI == EPI_QKV) {
      u16* P = (u16*)(seg == 0 ? C0 : (seg == 1 ? C1 : C2));
      *(uint4*)(P + m * 512 + (int)((n0 + nc) & 511)) = vv;
    } else if constexpr (EPI == EPI_KV) {
      u16* P = (u16*)(seg == 0 ? C0 : C1);
      *(uint4*)(P + m * 512 + (int)((n0 + nc) & 511)) = vv;
    } else if constexpr (EPI == EPI_BF16 || EPI == EPI_PHI) {
      *(uint4*)((u16*)C0 + m * Ns + n0 + nc) = vv;
    } else if constexpr (EPI == EPI_RESX) {
      const float* ax = (const float*)aux + m * Ns + n0 + nc;
      float4 a0 = *(const float4*)ax;
      float4 a1 = *(const float4*)(ax + 4);
      union { u16 u[8]; uint4 v; } o;
      o.u[0] = f2bf(a0.x + bf2f(vp[0]));
      o.u[1] = f2bf(a0.y + bf2f(vp[1]));
      o.u[2] = f2bf(a0.z + bf2f(vp[2]));
      o.u[3] = f2bf(a0.w + bf2f(vp[3]));
      o.u[4] = f2bf(a1.x + bf2f(vp[4]));
      o.u[5] = f2bf(a1.y + bf2f(vp[5]));
      o.u[6] = f2bf(a1.z + bf2f(vp[6]));
      o.u[7] = f2bf(a1.w + bf2f(vp[7]));
      *(uint4*)((u16*)C0 + m * Ns + n0 + nc) = o.v;
    } else if constexpr (EPI == EPI_RESH) {
      uint4 hh = *(const uint4*)((const u16*)aux + m * Ns + n0 + nc);
      const u16* hp = (const u16*)&hh;
      union { u16 u[8]; uint4 v; } o;
#pragma unroll
      for (int e = 0; e < 8; e++) o.u[e] = f2bf(bf2f(hp[e]) + bf2f(vp[e]));
      *(uint4*)((u16*)C0 + m * Ns + n0 + nc) = o.v;
    } else if constexpr (EPI == EPI_SILUMUL) {
      uint4 tt = *(const uint4*)((const u16*)aux + m * Ns + n0 + nc);
      const u16* tp = (const u16*)&tt;
      union { u16 u[8]; uint4 v; } o;
#pragma unroll
      for (int e = 0; e < 8; e++) {
        float t2 = bf2f(tp[e]);
        float s = t2 / (1.f + __expf(-t2));
        o.u[e] = f2bf(s * bf2f(vp[e]));
      }
      *(uint4*)((u16*)C0 + m * Ns + n0 + nc) = o.v;
    } else {  // EPI_OUTF
      uint4 hh = *(const uint4*)((const u16*)aux + m * Ns + n0 + nc);
      const u16* hp = (const u16*)&hh;
      float* o = (float*)C0 + m * Ns + n0 + nc;
      float4 o0, o1;
      o0.x = bf2f(hp[0]) + bf2f(vp[0]);
      o0.y = bf2f(hp[1]) + bf2f(vp[1]);
      o0.z = bf2f(hp[2]) + bf2f(vp[2]);
      o0.w = bf2f(hp[3]) + bf2f(vp[3]);
      o1.x = bf2f(hp[4]) + bf2f(vp[4]);
      o1.y = bf2f(hp[5]) + bf2f(vp[5]);
      o1.z = bf2f(hp[6]) + bf2f(vp[6]);
      o1.w = bf2f(hp[7]) + bf2f(vp[7]);
      *(float4*)o = o0;
      *(float4*)(o + 4) = o1;
    }
  }
}

// ---------------- fused attention, mode 1 (time): one WG per (b,n,h) --------
__launch_bounds__(256)
__global__ void att_mode1(const u16* __restrict__ q, const u16* __restrict__ k,
                          const u16* __restrict__ v, u16* __restrict__ attc) {
  __shared__ u32 KT[64][132];   // [dh][t-pair]; reused as O-stage [256][66] u16
  __shared__ u32 VT[64][132];
  __shared__ u16 KVT[64][72];
  __shared__ float ksump[4][64];
  __shared__ float ksum_s[64];
  __shared__ float dinv[256];
  const int tid = threadIdx.x;
  const int lane = tid & 63;
  const int w = tid >> 6;
  const int bnh = blockIdx.x;          // ((b*64+n)*8+h)
  const int h = bnh & 7;
  const int bn = bnh >> 3;
  const int n = bn & 63;
  const int b = bn >> 6;
  const long base = ((long)b * 16384 + n) * 512 + h * 64;   // + t*32768
  const int fr = lane & 15;
  const int frq = lane >> 4;
  const int fk = frq * 8;

#pragma unroll
  for (int r = 0; r < 4; r++) {
    const int tp = (tid & 63) + (r & 1) * 64;
    const int c8 = (tid >> 6) + (r >> 1) * 4;
    const long g0 = base + (long)(2 * tp) * 32768 + c8 * 8;
    uint4 ka = *(const uint4*)(k + g0);
    uint4 kb = *(const uint4*)(k + g0 + 32768);
    uint4 va = *(const uint4*)(v + g0);
    uint4 vb = *(const uint4*)(v + g0 + 32768);
    const u16* kap = (const u16*)&ka; const u16* kbp = (const u16*)&kb;
    const u16* vap = (const u16*)&va; const u16* vbp = (const u16*)&vb;
#pragma unroll
    for (int e = 0; e < 8; e++) {
      KT[c8 * 8 + e][tp] = (u32)kap[e] | ((u32)kbp[e] << 16);
      VT[c8 * 8 + e][tp] = (u32)vap[e] | ((u32)vbp[e] << 16);
    }
  }
  __syncthreads();

  {
    const int dk = tid >> 2, qq = tid & 3;
    float s = 0.f;
#pragma unroll
    for (int i = 0; i < 8; i++) {
      uint4 x = *(const uint4*)&KT[dk][qq * 32 + i * 4];
      s += bflo(x.x) + bfhi(x.x) + bflo(x.y) + bfhi(x.y)
         + bflo(x.z) + bfhi(x.z) + bflo(x.w) + bfhi(x.w);
    }
    ksump[qq][dk] = s;
  }

  f32x4 acc[4] = {};
#pragma unroll
  for (int ks = 0; ks < 8; ks++) {
    s16x8 af = *(const s16x8*)&VT[w * 16 + fr][ks * 16 + frq * 4];
    s16x8 bk[4];
#pragma unroll
    for (int j = 0; j < 4; j++)
      bk[j] = *(const s16x8*)&KT[j * 16 + fr][ks * 16 + frq * 4];
#pragma unroll
    for (int j = 0; j < 4; j++)
      acc[j] = __builtin_amdgcn_mfma_f32_16x16x32_bf16(af, bk[j], acc[j], 0, 0, 0);
  }
  __syncthreads();                     // KT/VT dead after this point
  {
    const int colL = lane & 15, rb = frq * 4;
#pragma unroll
    for (int j = 0; j < 4; j++)
#pragma unroll
      for (int r = 0; r < 4; r++)
        KVT[w * 16 + rb + r][j * 16 + colL] = f2bf(acc[j][r]);
  }
  if (tid < 64) ksum_s[tid] = ksump[0][tid] + ksump[1][tid] + ksump[2][tid] + ksump[3][tid];
  __syncthreads();
  {
    const u16* qp = q + base + (long)tid * 32768;
    float d = 0.f;
#pragma unroll
    for (int c8 = 0; c8 < 8; c8++) {
      uint4 u = ((const uint4*)qp)[c8];
      const u16* us = (const u16*)&u;
#pragma unroll
      for (int e = 0; e < 8; e++) d += bf2f(us[e]) * ksum_s[c8 * 8 + e];
    }
    dinv[tid] = 0.5f / (d + 1e-6f);
  }
  f32x4 acc2[4][4] = {};
#pragma unroll
  for (int ks = 0; ks < 2; ks++) {
    s16x8 aq[4], bk[4];
#pragma unroll
    for (int i = 0; i < 4; i++)
      aq[i] = *(const s16x8*)(q + base + (long)(w * 64 + i * 16 + fr) * 32768 + ks * 32 + fk);
#pragma unroll
    for (int j = 0; j < 4; j++)
      bk[j] = *(const s16x8*)&KVT[j * 16 + fr][ks * 32 + fk];
#pragma unroll
    for (int i = 0; i < 4; i++)
#pragma unroll
      for (int j = 0; j < 4; j++)
        acc2[i][j] = __builtin_amdgcn_mfma_f32_16x16x32_bf16(aq[i], bk[j], acc2[i][j], 0, 0, 0);
  }
  __syncthreads();   // dinv ready
  // stage O (scaled) into dead KT area: Osm[256][66] u16 = 33792 B == sizeof(KT)
  u16* Osm = (u16*)&KT[0][0];
  const int colL = lane & 15, rb = frq * 4;
#pragma unroll
  for (int i = 0; i < 4; i++)
#pragma unroll
    for (int r = 0; r < 4; r++) {
      int t = w * 64 + i * 16 + rb + r;
      float inv = dinv[t];
#pragma unroll
      for (int j = 0; j < 4; j++)
        Osm[t * 66 + j * 16 + colL] = f2bf(acc2[i][j][r] * inv);
    }
  __syncthreads();
#pragma unroll
  for (int rep = 0; rep < 8; rep++) {
    const int idx = rep * 256 + tid;
    const int t = idx >> 3;
    const int c8 = (idx & 7) * 8;
    *(uint4*)(attc + base + (long)t * 32768 + c8) = *(const uint4*)&Osm[t * 66 + c8];
  }
}

// ---------------- fused attention, mode 2 (entities): one WG per (b,t,h) ----
__launch_bounds__(256)
__global__ void att_mode2(const u16* __restrict__ q, const u16* __restrict__ k,
                          const u16* __restrict__ v, u16* __restrict__ attc) {
  __shared__ u32 KT[64][36];    // reused as O-stage [64][66] u16 = 8448 B <= 9216
  __shared__ u32 VT[64][36];
  __shared__ u16 KVT[64][72];
  __shared__ float ksump[4][64];
  __shared__ float ksum_s[64];
  __shared__ float dinv[64];
  const int tid = threadIdx.x;
  const int lane = tid & 63;
  const int w = tid >> 6;
  const int bth = blockIdx.x;
  const int h = bth & 7;
  const long bt = bth >> 3;
  const long base = bt * 32768 + h * 64;
  const int fr = lane & 15;
  const int frq = lane >> 4;
  const int fk = frq * 8;

  {
    const int np = tid & 31;
    const int c8 = tid >> 5;
    const long g0 = base + (long)(2 * np) * 512 + c8 * 8;
    uint4 ka = *(const uint4*)(k + g0);
    uint4 kb = *(const uint4*)(k + g0 + 512);
    uint4 va = *(const uint4*)(v + g0);
    uint4 vb = *(const uint4*)(v + g0 + 512);
    const u16* kap = (const u16*)&ka; const u16* kbp = (const u16*)&kb;
    const u16* vap = (const u16*)&va; const u16* vbp = (const u16*)&vb;
#pragma unroll
    for (int e = 0; e < 8; e++) {
      KT[c8 * 8 + e][np] = (u32)kap[e] | ((u32)kbp[e] << 16);
      VT[c8 * 8 + e][np] = (u32)vap[e] | ((u32)vbp[e] << 16);
    }
  }
  __syncthreads();
  {
    const int dk = tid >> 2, qq = tid & 3;
    uint4 x0 = *(const uint4*)&KT[dk][qq * 8];
    uint4 x1 = *(const uint4*)&KT[dk][qq * 8 + 4];
    float s = bflo(x0.x) + bfhi(x0.x) + bflo(x0.y) + bfhi(x0.y)
            + bflo(x0.z) + bfhi(x0.z) + bflo(x0.w) + bfhi(x0.w)
            + bflo(x1.x) + bfhi(x1.x) + bflo(x1.y) + bfhi(x1.y)
            + bflo(x1.z) + bfhi(x1.z) + bflo(x1.w) + bfhi(x1.w);
    ksump[qq][dk] = s;
  }
  f32x4 acc[4] = {};
#pragma unroll
  for (int ks = 0; ks < 2; ks++) {
    s16x8 af = *(const s16x8*)&VT[w * 16 + fr][ks * 16 + frq * 4];
    s16x8 bk[4];
#pragma unroll
    for (int j = 0; j < 4; j++)
      bk[j] = *(const s16x8*)&KT[j * 16 + fr][ks * 16 + frq * 4];
#pragma unroll
    for (int j = 0; j < 4; j++)
      acc[j] = __builtin_amdgcn_mfma_f32_16x16x32_bf16(af, bk[j], acc[j], 0, 0, 0);
  }
  __syncthreads();                     // KT/VT dead after this point
  {
    const int colL = lane & 15, rb = frq * 4;
#pragma unroll
    for (int j = 0; j < 4; j++)
#pragma unroll
      for (int r = 0; r < 4; r++)
        KVT[w * 16 + rb + r][j * 16 + colL] = f2bf(acc[j][r]);
  }
  if (tid < 64) ksum_s[tid] = ksump[0][tid] + ksump[1][tid] + ksump[2][tid] + ksump[3][tid];
  __syncthreads();
  if (tid < 64) {
    const u16* qp = q + base + (long)tid * 512;
    float d = 0.f;
#pragma unroll
    for (int c8 = 0; c8 < 8; c8++) {
      uint4 u = ((const uint4*)qp)[c8];
      const u16* us = (const u16*)&u;
#pragma unroll
      for (int e = 0; e < 8; e++) d += bf2f(us[e]) * ksum_s[c8 * 8 + e];
    }
    dinv[tid] = 0.5f / (d + 1e-6f);
  }
  f32x4 acc2[4] = {};
#pragma unroll
  for (int ks = 0; ks < 2; ks++) {
    s16x8 aq, bk[4];
    aq = *(const s16x8*)(q + base + (long)(w * 16 + fr) * 512 + ks * 32 + fk);
#pragma unroll
    for (int j = 0; j < 4; j++)
      bk[j] = *(const s16x8*)&KVT[j * 16 + fr][ks * 32 + fk];
#pragma unroll
    for (int j = 0; j < 4; j++)
      acc2[j] = __builtin_amdgcn_mfma_f32_16x16x32_bf16(aq, bk[j], acc2[j], 0, 0, 0);
  }
  __syncthreads();   // dinv ready
  // stage contribution into dead KT area: Osm[64][66] u16
  u16* Osm = (u16*)&KT[0][0];
  const int colL = lane & 15, rb = frq * 4;
#pragma unroll
  for (int r = 0; r < 4; r++) {
    int nr = w * 16 + rb + r;
    float inv = dinv[nr];
#pragma unroll
    for (int j = 0; j < 4; j++)
      Osm[nr * 66 + j * 16 + colL] = f2bf(acc2[j][r] * inv);
  }
  __syncthreads();
#pragma unroll
  for (int rep = 0; rep < 2; rep++) {
    const int idx = rep * 256 + tid;
    const int nr = idx >> 3;
    const int c8 = (idx & 7) * 8;
    u16* dst = attc + base + (long)nr * 512 + c8;
    uint4 old = *(const uint4*)dst;
    uint4 cv = *(const uint4*)&Osm[nr * 66 + c8];
    const u16* op = (const u16*)&old;
    const u16* cp = (const u16*)&cv;
    union { u16 u[8]; uint4 v; } o;
#pragma unroll
    for (int e = 0; e < 8; e++) o.u[e] = f2bf(bf2f(op[e]) + bf2f(cp[e]));
    *(uint4*)dst = o.v;
  }
}

// ============================================================================
extern "C" void kernel_launch(void* const* d_in, const int* in_sizes, int n_in,
                              void* d_out, int out_size, void* d_ws, size_t ws_size,
                              hipStream_t stream) {
  const float* X    = (const float*)d_in[0];
  const float* Z    = (const float*)d_in[1];
  const float* n1   = (const float*)d_in[2];
  const float* n2   = (const float*)d_in[3];
  const float* n3   = (const float*)d_in[4];
  const float* nz   = (const float*)d_in[5];
  const float* a_wq = (const float*)d_in[6];
  const float* a_wk = (const float*)d_in[7];
  const float* a_wv = (const float*)d_in[8];
  const float* a_wo = (const float*)d_in[9];
  const float* c_wq = (const float*)d_in[10];
  const float* c_wk = (const float*)d_in[11];
  const float* c_wv = (const float*)d_in[12];
  const float* c_wo = (const float*)d_in[13];
  const float* f_w1 = (const float*)d_in[14];
  const float* f_w2 = (const float*)d_in[15];
  const float* f_w3 = (const float*)d_in[16];
  float* out = (float*)d_out;
  (void)ws_size; (void)in_sizes; (void)n_in; (void)out_size;

  char* p = (char*)d_ws;
  size_t off = 0;
  auto take = [&](size_t bytes) -> char* {
    char* r = p + off;
    off += (bytes + 255) & ~(size_t)255;
    return r;
  };
  // w_aq/w_ak/w_av contiguous => stacked [1536][512] QKV weight; w_ck/w_cv => [1024][512].
  u16* w_aq = (u16*)take(512 * 512 * 2);
  u16* w_ak = (u16*)take(512 * 512 * 2);
  u16* w_av = (u16*)take(512 * 512 * 2);
  u16* w_ao = (u16*)take(512 * 512 * 2);
  u16* w_cq = (u16*)take(512 * 512 * 2);   // gamma n3 folded
  u16* w_ck = (u16*)take(512 * 512 * 2);
  u16* w_cv = (u16*)take(512 * 512 * 2);
  u16* w_co = (u16*)take(512 * 512 * 2);
  u16* w_f1 = (u16*)take(2048 * 512 * 2);  // gamma n2 folded
  u16* w_f3 = (u16*)take(2048 * 512 * 2);  // gamma n2 folded
  u16* w_f2 = (u16*)take(512 * 2048 * 2);
  u16* xn   = (u16*)take((size_t)65536 * 512 * 2);   // normed input; attc aliases
  u16* hbuf = (u16*)take((size_t)65536 * 512 * 2);   // bf16 residual h
  u16* qbuf = (u16*)take((size_t)65536 * 512 * 2);   // q; FFN hidden chunk aliases
  float* shs = (float*)take((size_t)65536 * 4);      // h row scales
  // d_out as scratch (128 MiB): k | v  (dead before phase 3 writes out)
  u16* kbuf = (u16*)d_out;
  u16* vbuf = (u16*)d_out + (size_t)65536 * 512;
  u16* attc = xn;     // alias: normed input dead once projections done
  u16* tslot = qbuf;  // FFN: [16384][2048] bf16 chunk = 64 MiB

  dim3 b256(256);
  dim3 gQKV(12, 512);  // Ns=1536 fused qkv -> 6144 blocks
  dim3 gKV(8, 512);    // Ns=1024 fused kv  -> 4096 blocks
  dim3 gP(4, 512);     // N=512, M=65536    -> 2048 blocks
  dim3 gU(16, 128);    // N=2048, M=16384   -> 2048 blocks
  dim3 gD(4, 128);     // N=512, M=16384    -> 512 blocks

  // weight prep (gamma folded where the GEMM consumes un-normed bf16 h)
  wprep<512, 512><<<64, b256, 0, stream>>>(a_wq, w_aq, nullptr);
  wprep<512, 512><<<64, b256, 0, stream>>>(a_wk, w_ak, nullptr);
  wprep<512, 512><<<64, b256, 0, stream>>>(a_wv, w_av, nullptr);
  wprep<512, 512><<<64, b256, 0, stream>>>(a_wo, w_ao, nullptr);
  wprep<512, 512><<<64, b256, 0, stream>>>(c_wq, w_cq, n3);
  wprep<512, 512><<<64, b256, 0, stream>>>(c_wk, w_ck, nullptr);
  wprep<512, 512><<<64, b256, 0, stream>>>(c_wv, w_cv, nullptr);
  wprep<512, 512><<<64, b256, 0, stream>>>(c_wo, w_co, nullptr);
  wprep<512, 2048><<<256, b256, 0, stream>>>(f_w1, w_f1, n2);
  wprep<512, 2048><<<256, b256, 0, stream>>>(f_w3, w_f3, n2);
  wprep<2048, 512><<<256, b256, 0, stream>>>(f_w2, w_f2, nullptr);

  // ---------------- Phase 1: h = X + SelfAtt(norm1(X)) ----------------------
  rmsnorm_f32<<<16384, b256, 0, stream>>>(X, n1, xn);
  gemm128<512, EPI_QKV><<<gQKV, b256, 0, stream>>>(xn, w_aq, qbuf, kbuf, vbuf, nullptr, 1536, nullptr);
  att_mode1<<<2048, b256, 0, stream>>>(qbuf, kbuf, vbuf, attc);
  att_mode2<<<8192, b256, 0, stream>>>(qbuf, kbuf, vbuf, attc);
  gemm128<512, EPI_RESX><<<gP, b256, 0, stream>>>(attc, w_ao, hbuf, nullptr, nullptr, X, 512, nullptr);

  // ---------------- Phase 2: h += CrossAtt(norm3(h), normz(Z)) --------------
  rowscale_bf16<<<16384, b256, 0, stream>>>(hbuf, shs);
  gemm128<512, EPI_PHI><<<gP, b256, 0, stream>>>(hbuf, w_cq, qbuf, nullptr, nullptr, nullptr, 512, shs);
  rmsnorm_f32<<<16384, b256, 0, stream>>>(Z, nz, xn);
  gemm128<512, EPI_KV><<<gKV, b256, 0, stream>>>(xn, w_ck, kbuf, vbuf, nullptr, nullptr, 1024, nullptr);
  att_mode1<<<2048, b256, 0, stream>>>(qbuf, kbuf, vbuf, attc);
  att_mode2<<<8192, b256, 0, stream>>>(qbuf, kbuf, vbuf, attc);
  gemm128<512, EPI_RESH><<<gP, b256, 0, stream>>>(attc, w_co, hbuf, nullptr, nullptr, hbuf, 512, nullptr);

  // ---------------- Phase 3: out = h + SwiGLU(norm2(h)) ---------------------
  rowscale_bf16<<<16384, b256, 0, stream>>>(hbuf, shs);
  const int CH = 16384;
  for (int c = 0; c < 4; c++) {
    const size_t ro = (size_t)c * CH * 512;
    gemm128<512, EPI_BF16><<<gU, b256, 0, stream>>>(hbuf + ro, w_f1, tslot, nullptr, nullptr, nullptr, 2048, shs + (size_t)c * CH);
    gemm128<512, EPI_SILUMUL><<<gU, b256, 0, stream>>>(hbuf + ro, w_f3, tslot, nullptr, nullptr, tslot, 2048, shs + (size_t)c * CH);
    gemm128<2048, EPI_OUTF><<<gD, b256, 0, stream>>>(tslot, w_f2, out + ro, nullptr, nullptr, hbuf + ro, 512, nullptr);
  }
}

// Round 18
// 1422.688 us; speedup vs baseline: 1.0632x; 1.0632x over previous
//
#include <hip/hip_runtime.h>

typedef short s16x8 __attribute__((ext_vector_type(8)));
typedef float f32x4 __attribute__((ext_vector_type(4)));
typedef unsigned short u16;
typedef unsigned int u32;

__device__ __forceinline__ float bf2f(u16 u) {
  union { unsigned int i; float f; } v; v.i = ((unsigned int)u) << 16; return v.f;
}
__device__ __forceinline__ u16 f2bf(float f) {
  union { float f; unsigned int i; } v; v.f = f;
  unsigned int r = v.i + 0x7fffu + ((v.i >> 16) & 1u);
  return (u16)(r >> 16);
}
__device__ __forceinline__ float bflo(u32 x) {
  union { unsigned int i; float f; } v; v.i = x << 16; return v.f;
}
__device__ __forceinline__ float bfhi(u32 x) {
  union { unsigned int i; float f; } v; v.i = x & 0xffff0000u; return v.f;
}

// async global->LDS, 16B per lane. LDS dest must be wave-uniform; HW adds lane*16.
__device__ __forceinline__ void gload16(const u16* g, u16* l) {
  __builtin_amdgcn_global_load_lds(
      (const __attribute__((address_space(1))) u32*)g,
      (__attribute__((address_space(3))) u32*)l, 16, 0, 0);
}

// ---------------- weight transpose + cast: in[K][N] f32 -> out[N][K] bf16 ----
template<int KDIM, int NDIM>
__launch_bounds__(256)
__global__ void wprep(const float* __restrict__ in, u16* __restrict__ out) {
  __shared__ float t[64][65];
  const int tid = threadIdx.x;
  const int nb = NDIM / 64;
  const int tk0 = (blockIdx.x / nb) * 64;
  const int tn0 = (blockIdx.x % nb) * 64;
#pragma unroll
  for (int i = 0; i < 16; i++) {
    int idx = i * 256 + tid;
    int r = idx >> 6, c = idx & 63;
    t[r][c] = in[(long)(tk0 + r) * NDIM + (tn0 + c)];
  }
  __syncthreads();
#pragma unroll
  for (int i = 0; i < 16; i++) {
    int idx = i * 256 + tid;
    int nn = idx >> 6, kk = idx & 63;
    out[(long)(tn0 + nn) * KDIM + (tk0 + kk)] = f2bf(t[kk][nn]);
  }
}

// ---------------- rmsnorm (f32 src) + cast to bf16 --------------------------
__launch_bounds__(256)
__global__ void rmsnorm_f32(const float* __restrict__ x, const float* __restrict__ w,
                            u16* __restrict__ out) {
  const long row = (long)blockIdx.x * 4 + (threadIdx.x >> 6);
  const int lane = threadIdx.x & 63;
  const float* xr = x + row * 512 + lane * 8;
  float4 v0 = *(const float4*)xr;
  float4 v1 = *(const float4*)(xr + 4);
  float ss = v0.x*v0.x + v0.y*v0.y + v0.z*v0.z + v0.w*v0.w
           + v1.x*v1.x + v1.y*v1.y + v1.z*v1.z + v1.w*v1.w;
#pragma unroll
  for (int o = 1; o < 64; o <<= 1) ss += __shfl_xor(ss, o);
  float sc = rsqrtf(ss * (1.0f / 512.0f) + 1e-6f);
  const float* wp = w + lane * 8;
  float4 w0 = *(const float4*)wp;
  float4 w1 = *(const float4*)(wp + 4);
  union { u16 u[8]; uint4 v; } o;
  o.u[0] = f2bf(v0.x * sc * w0.x);
  o.u[1] = f2bf(v0.y * sc * w0.y);
  o.u[2] = f2bf(v0.z * sc * w0.z);
  o.u[3] = f2bf(v0.w * sc * w0.w);
  o.u[4] = f2bf(v1.x * sc * w1.x);
  o.u[5] = f2bf(v1.y * sc * w1.y);
  o.u[6] = f2bf(v1.z * sc * w1.z);
  o.u[7] = f2bf(v1.w * sc * w1.w);
  *(uint4*)(out + row * 512 + lane * 8) = o.v;
}

// ---------------- rmsnorm (bf16 src) + cast to bf16 -------------------------
__launch_bounds__(256)
__global__ void rmsnorm_bf16(const u16* __restrict__ x, const float* __restrict__ w,
                             u16* __restrict__ out) {
  const long row = (long)blockIdx.x * 4 + (threadIdx.x >> 6);
  const int lane = threadIdx.x & 63;
  uint4 u = *(const uint4*)(x + row * 512 + lane * 8);
  const u16* us = (const u16*)&u;
  float f[8];
  float ss = 0.f;
#pragma unroll
  for (int j = 0; j < 8; j++) { f[j] = bf2f(us[j]); ss += f[j] * f[j]; }
#pragma unroll
  for (int o = 1; o < 64; o <<= 1) ss += __shfl_xor(ss, o);
  float sc = rsqrtf(ss * (1.0f / 512.0f) + 1e-6f);
  const float* wp = w + lane * 8;
  union { u16 u[8]; uint4 v; } o;
#pragma unroll
  for (int j = 0; j < 8; j++) o.u[j] = f2bf(f[j] * sc * wp[j]);
  *(uint4*)(out + row * 512 + lane * 8) = o.v;
}

// ---- 128x128 dbuf counted-vmcnt GEMM + LDS-staged coalesced epilogue --------
enum { EPI_BF16 = 0, EPI_PHI = 1, EPI_RESX = 2, EPI_RESH = 3, EPI_SILUMUL = 4,
       EPI_OUTF = 5, EPI_QKV = 6, EPI_KV = 7 };

template<int KD, int EPI>
__launch_bounds__(256)
__global__ void gemm128(const u16* __restrict__ A, const u16* __restrict__ Bt,
                        void* __restrict__ C0, void* __restrict__ C1,
                        void* __restrict__ C2, const void* __restrict__ aux,
                        int Ns) {
  __shared__ u16 smem[32768];           // 64 KB: As|Bs during loop, Cs in epilogue
  u16* Asm = smem;                      // [2][128][64]
  u16* Bsm = smem + 16384;
  const int tid = threadIdx.x;
  const int lane = tid & 63;
  const int wv = tid >> 6;
  const int gx = gridDim.x;
  int L = blockIdx.y * gx + blockIdx.x;
  const int cpx = (gx * gridDim.y) >> 3;
  L = (L & 7) * cpx + (L >> 3);
  const long m0 = (long)(L / gx) * 128;
  const int nb = L % gx;
  const long n0 = (long)nb * 128;

  const int wr = (wv >> 1) * 64;
  const int wc = (wv & 1) * 64;
  const int fr = lane & 15;
  const int frq = lane >> 4;

  const int r0 = wv * 32 + (lane >> 3);
  const int sg8 = ((lane & 7) ^ ((lane >> 3) & 7)) * 8;
  const u16* Ag = A + (m0 + r0) * KD + sg8;
  const u16* Bg = Bt + (n0 + r0) * KD + sg8;
  u16* Alds = Asm + wv * 2048;
  u16* Blds = Bsm + wv * 2048;

  f32x4 acc[4][4] = {};

  auto STAGE = [&](int b, int kt) {
    const long k0 = (long)kt * 64;
#pragma unroll
    for (int j = 0; j < 4; j++) {
      gload16(Ag + (long)(j * 8) * KD + k0, Alds + b * 8192 + j * 512);
      gload16(Bg + (long)(j * 8) * KD + k0, Blds + b * 8192 + j * 512);
    }
  };
  auto COMPUTE = [&](int b) {
#pragma unroll
    for (int ks = 0; ks < 2; ks++) {
      const int slot = ((ks * 4 + frq) ^ (fr & 7)) * 8;
      s16x8 af[4], bf[4];
#pragma unroll
      for (int i = 0; i < 4; i++)
        af[i] = *(const s16x8*)&Asm[b * 8192 + (wr + i * 16 + fr) * 64 + slot];
#pragma unroll
      for (int j = 0; j < 4; j++)
        bf[j] = *(const s16x8*)&Bsm[b * 8192 + (wc + j * 16 + fr) * 64 + slot];
#pragma unroll
      for (int i = 0; i < 4; i++)
#pragma unroll
        for (int j = 0; j < 4; j++)
          acc[i][j] = __builtin_amdgcn_mfma_f32_16x16x32_bf16(af[i], bf[j], acc[i][j], 0, 0, 0);
    }
  };

  constexpr int NT = KD / 64;
  STAGE(0, 0);
#pragma unroll 1
  for (int t = 0; t < NT; ++t) {
    if (t + 1 < NT) {
      STAGE((t + 1) & 1, t + 1);
      asm volatile("s_waitcnt vmcnt(8)" ::: "memory");
    } else {
      asm volatile("s_waitcnt vmcnt(0)" ::: "memory");
    }
    __builtin_amdgcn_s_barrier();
    COMPUTE(t & 1);
    asm volatile("s_waitcnt lgkmcnt(0)" ::: "memory");
    __builtin_amdgcn_s_barrier();
  }

  // ---- epilogue: stage C-tile bf16 in LDS, then coalesced 16B stores ----
  u16* Cs = smem;
  const int col = lane & 15;
  const int rb = frq * 4;
  const int seg = (EPI == EPI_QKV || EPI == EPI_KV) ? (nb >> 2) : 0;
#pragma unroll
  for (int i = 0; i < 4; i++) {
#pragma unroll
    for (int r = 0; r < 4; r++) {
      const int ml = wr + i * 16 + rb + r;
#pragma unroll
      for (int j = 0; j < 4; j++) {
        const int nl = wc + j * 16 + col;
        float v = acc[i][j][r];
        if constexpr (EPI == EPI_PHI) {
          v = v > 0.f ? v + 1.f : __expf(v);
        } else if constexpr (EPI == EPI_QKV) {
          if (seg < 2) v = v > 0.f ? v + 1.f : __expf(v);
        } else if constexpr (EPI == EPI_KV) {
          if (seg == 0) v = v > 0.f ? v + 1.f : __expf(v);
        }
        Cs[ml * 148 + nl] = f2bf(v);
      }
    }
  }
  __syncthreads();

#pragma unroll
  for (int rep = 0; rep < 8; rep++) {
    const int idx = rep * 256 + tid;
    const int row = idx >> 4;
    const int nc = (idx & 15) * 8;      // tile col of this 16B chunk
    const long m = m0 + row;
    uint4 vv = *(const uint4*)&Cs[row * 148 + nc];
    const u16* vp = (const u16*)&vv;
    if constexpr (EPI == EPI_QKV) {
      u16* P = (u16*)(seg == 0 ? C0 : (seg == 1 ? C1 : C2));
      *(uint4*)(P + m * 512 + (int)((n0 + nc) & 511)) = vv;
    } else if constexpr (EPI == EPI_KV) {
      u16* P = (u16*)(seg == 0 ? C0 : C1);
      *(uint4*)(P + m * 512 + (int)((n0 + nc) & 511)) = vv;
    } else if constexpr (EPI == EPI_BF16 || EPI == EPI_PHI) {
      *(uint4*)((u16*)C0 + m * Ns + n0 + nc) = vv;
    } else if constexpr (EPI == EPI_RESX) {
      const float* ax = (const float*)aux + m * Ns + n0 + nc;
      float4 a0 = *(const float4*)ax;
      float4 a1 = *(const float4*)(ax + 4);
      union { u16 u[8]; uint4 v; } o;
      o.u[0] = f2bf(a0.x + bf2f(vp[0]));
      o.u[1] = f2bf(a0.y + bf2f(vp[1]));
      o.u[2] = f2bf(a0.z + bf2f(vp[2]));
      o.u[3] = f2bf(a0.w + bf2f(vp[3]));
      o.u[4] = f2bf(a1.x + bf2f(vp[4]));
      o.u[5] = f2bf(a1.y + bf2f(vp[5]));
      o.u[6] = f2bf(a1.z + bf2f(vp[6]));
      o.u[7] = f2bf(a1.w + bf2f(vp[7]));
      *(uint4*)((u16*)C0 + m * Ns + n0 + nc) = o.v;
    } else if constexpr (EPI == EPI_RESH) {
      uint4 hh = *(const uint4*)((const u16*)aux + m * Ns + n0 + nc);
      const u16* hp = (const u16*)&hh;
      union { u16 u[8]; uint4 v; } o;
#pragma unroll
      for (int e = 0; e < 8; e++) o.u[e] = f2bf(bf2f(hp[e]) + bf2f(vp[e]));
      *(uint4*)((u16*)C0 + m * Ns + n0 + nc) = o.v;
    } else if constexpr (EPI == EPI_SILUMUL) {
      uint4 tt = *(const uint4*)((const u16*)aux + m * Ns + n0 + nc);
      const u16* tp = (const u16*)&tt;
      union { u16 u[8]; uint4 v; } o;
#pragma unroll
      for (int e = 0; e < 8; e++) {
        float t2 = bf2f(tp[e]);
        float s = t2 / (1.f + __expf(-t2));
        o.u[e] = f2bf(s * bf2f(vp[e]));
      }
      *(uint4*)((u16*)C0 + m * Ns + n0 + nc) = o.v;
    } else {  // EPI_OUTF
      uint4 hh = *(const uint4*)((const u16*)aux + m * Ns + n0 + nc);
      const u16* hp = (const u16*)&hh;
      float* o = (float*)C0 + m * Ns + n0 + nc;
      float4 o0, o1;
      o0.x = bf2f(hp[0]) + bf2f(vp[0]);
      o0.y = bf2f(hp[1]) + bf2f(vp[1]);
      o0.z = bf2f(hp[2]) + bf2f(vp[2]);
      o0.w = bf2f(hp[3]) + bf2f(vp[3]);
      o1.x = bf2f(hp[4]) + bf2f(vp[4]);
      o1.y = bf2f(hp[5]) + bf2f(vp[5]);
      o1.z = bf2f(hp[6]) + bf2f(vp[6]);
      o1.w = bf2f(hp[7]) + bf2f(vp[7]);
      *(float4*)o = o0;
      *(float4*)(o + 4) = o1;
    }
  }
}

// ---------------- fused attention, mode 1 (time): one WG per (b,n,h) --------
// O staged through dead KT area -> coalesced 16B stores.
__launch_bounds__(256)
__global__ void att_mode1(const u16* __restrict__ q, const u16* __restrict__ k,
                          const u16* __restrict__ v, u16* __restrict__ attc) {
  __shared__ u32 KT[64][132];   // [dh][t-pair]; reused as O-stage [256][66] u16
  __shared__ u32 VT[64][132];
  __shared__ u16 KVT[64][72];
  __shared__ float ksump[4][64];
  __shared__ float ksum_s[64];
  __shared__ float dinv[256];
  const int tid = threadIdx.x;
  const int lane = tid & 63;
  const int w = tid >> 6;
  const int bnh = blockIdx.x;          // ((b*64+n)*8+h)
  const int h = bnh & 7;
  const int bn = bnh >> 3;
  const int n = bn & 63;
  const int b = bn >> 6;
  const long base = ((long)b * 16384 + n) * 512 + h * 64;   // + t*32768
  const int fr = lane & 15;
  const int frq = lane >> 4;
  const int fk = frq * 8;

#pragma unroll
  for (int r = 0; r < 4; r++) {
    const int tp = (tid & 63) + (r & 1) * 64;
    const int c8 = (tid >> 6) + (r >> 1) * 4;
    const long g0 = base + (long)(2 * tp) * 32768 + c8 * 8;
    uint4 ka = *(const uint4*)(k + g0);
    uint4 kb = *(const uint4*)(k + g0 + 32768);
    uint4 va = *(const uint4*)(v + g0);
    uint4 vb = *(const uint4*)(v + g0 + 32768);
    const u16* kap = (const u16*)&ka; const u16* kbp = (const u16*)&kb;
    const u16* vap = (const u16*)&va; const u16* vbp = (const u16*)&vb;
#pragma unroll
    for (int e = 0; e < 8; e++) {
      KT[c8 * 8 + e][tp] = (u32)kap[e] | ((u32)kbp[e] << 16);
      VT[c8 * 8 + e][tp] = (u32)vap[e] | ((u32)vbp[e] << 16);
    }
  }
  __syncthreads();

  {
    const int dk = tid >> 2, qq = tid & 3;
    float s = 0.f;
#pragma unroll
    for (int i = 0; i < 8; i++) {
      uint4 x = *(const uint4*)&KT[dk][qq * 32 + i * 4];
      s += bflo(x.x) + bfhi(x.x) + bflo(x.y) + bfhi(x.y)
         + bflo(x.z) + bfhi(x.z) + bflo(x.w) + bfhi(x.w);
    }
    ksump[qq][dk] = s;
  }

  f32x4 acc[4] = {};
#pragma unroll
  for (int ks = 0; ks < 8; ks++) {
    s16x8 af = *(const s16x8*)&VT[w * 16 + fr][ks * 16 + frq * 4];
    s16x8 bk[4];
#pragma unroll
    for (int j = 0; j < 4; j++)
      bk[j] = *(const s16x8*)&KT[j * 16 + fr][ks * 16 + frq * 4];
#pragma unroll
    for (int j = 0; j < 4; j++)
      acc[j] = __builtin_amdgcn_mfma_f32_16x16x32_bf16(af, bk[j], acc[j], 0, 0, 0);
  }
  __syncthreads();                     // KT/VT dead after this point
  {
    const int colL = lane & 15, rb = frq * 4;
#pragma unroll
    for (int j = 0; j < 4; j++)
#pragma unroll
      for (int r = 0; r < 4; r++)
        KVT[w * 16 + rb + r][j * 16 + colL] = f2bf(acc[j][r]);
  }
  if (tid < 64) ksum_s[tid] = ksump[0][tid] + ksump[1][tid] + ksump[2][tid] + ksump[3][tid];
  __syncthreads();
  {
    const u16* qp = q + base + (long)tid * 32768;
    float d = 0.f;
#pragma unroll
    for (int c8 = 0; c8 < 8; c8++) {
      uint4 u = ((const uint4*)qp)[c8];
      const u16* us = (const u16*)&u;
#pragma unroll
      for (int e = 0; e < 8; e++) d += bf2f(us[e]) * ksum_s[c8 * 8 + e];
    }
    dinv[tid] = 0.5f / (d + 1e-6f);
  }
  f32x4 acc2[4][4] = {};
#pragma unroll
  for (int ks = 0; ks < 2; ks++) {
    s16x8 aq[4], bk[4];
#pragma unroll
    for (int i = 0; i < 4; i++)
      aq[i] = *(const s16x8*)(q + base + (long)(w * 64 + i * 16 + fr) * 32768 + ks * 32 + fk);
#pragma unroll
    for (int j = 0; j < 4; j++)
      bk[j] = *(const s16x8*)&KVT[j * 16 + fr][ks * 32 + fk];
#pragma unroll
    for (int i = 0; i < 4; i++)
#pragma unroll
      for (int j = 0; j < 4; j++)
        acc2[i][j] = __builtin_amdgcn_mfma_f32_16x16x32_bf16(aq[i], bk[j], acc2[i][j], 0, 0, 0);
  }
  __syncthreads();   // dinv ready
  // stage O (scaled) into dead KT area: Osm[256][66] u16 = 33792 B == sizeof(KT)
  u16* Osm = (u16*)&KT[0][0];
  const int colL = lane & 15, rb = frq * 4;
#pragma unroll
  for (int i = 0; i < 4; i++)
#pragma unroll
    for (int r = 0; r < 4; r++) {
      int t = w * 64 + i * 16 + rb + r;
      float inv = dinv[t];
#pragma unroll
      for (int j = 0; j < 4; j++)
        Osm[t * 66 + j * 16 + colL] = f2bf(acc2[i][j][r] * inv);
    }
  __syncthreads();
#pragma unroll
  for (int rep = 0; rep < 8; rep++) {
    const int idx = rep * 256 + tid;
    const int t = idx >> 3;
    const int c8 = (idx & 7) * 8;
    *(uint4*)(attc + base + (long)t * 32768 + c8) = *(const uint4*)&Osm[t * 66 + c8];
  }
}

// ---------------- fused attention, mode 2 (entities): one WG per (b,t,h) ----
// O contribution staged through dead KT area -> coalesced 16B RMW.
__launch_bounds__(256)
__global__ void att_mode2(const u16* __restrict__ q, const u16* __restrict__ k,
                          const u16* __restrict__ v, u16* __restrict__ attc) {
  __shared__ u32 KT[64][36];    // reused as O-stage [64][66] u16 = 8448 B <= 9216
  __shared__ u32 VT[64][36];
  __shared__ u16 KVT[64][72];
  __shared__ float ksump[4][64];
  __shared__ float ksum_s[64];
  __shared__ float dinv[64];
  const int tid = threadIdx.x;
  const int lane = tid & 63;
  const int w = tid >> 6;
  const int bth = blockIdx.x;
  const int h = bth & 7;
  const long bt = bth >> 3;
  const long base = bt * 32768 + h * 64;
  const int fr = lane & 15;
  const int frq = lane >> 4;
  const int fk = frq * 8;

  {
    const int np = tid & 31;
    const int c8 = tid >> 5;
    const long g0 = base + (long)(2 * np) * 512 + c8 * 8;
    uint4 ka = *(const uint4*)(k + g0);
    uint4 kb = *(const uint4*)(k + g0 + 512);
    uint4 va = *(const uint4*)(v + g0);
    uint4 vb = *(const uint4*)(v + g0 + 512);
    const u16* kap = (const u16*)&ka; const u16* kbp = (const u16*)&kb;
    const u16* vap = (const u16*)&va; const u16* vbp = (const u16*)&vb;
#pragma unroll
    for (int e = 0; e < 8; e++) {
      KT[c8 * 8 + e][np] = (u32)kap[e] | ((u32)kbp[e] << 16);
      VT[c8 * 8 + e][np] = (u32)vap[e] | ((u32)vbp[e] << 16);
    }
  }
  __syncthreads();
  {
    const int dk = tid >> 2, qq = tid & 3;
    uint4 x0 = *(const uint4*)&KT[dk][qq * 8];
    uint4 x1 = *(const uint4*)&KT[dk][qq * 8 + 4];
    float s = bflo(x0.x) + bfhi(x0.x) + bflo(x0.y) + bfhi(x0.y)
            + bflo(x0.z) + bfhi(x0.z) + bflo(x0.w) + bfhi(x0.w)
            + bflo(x1.x) + bfhi(x1.x) + bflo(x1.y) + bfhi(x1.y)
            + bflo(x1.z) + bfhi(x1.z) + bflo(x1.w) + bfhi(x1.w);
    ksump[qq][dk] = s;
  }
  f32x4 acc[4] = {};
#pragma unroll
  for (int ks = 0; ks < 2; ks++) {
    s16x8 af = *(const s16x8*)&VT[w * 16 + fr][ks * 16 + frq * 4];
    s16x8 bk[4];
#pragma unroll
    for (int j = 0; j < 4; j++)
      bk[j] = *(const s16x8*)&KT[j * 16 + fr][ks * 16 + frq * 4];
#pragma unroll
    for (int j = 0; j < 4; j++)
      acc[j] = __builtin_amdgcn_mfma_f32_16x16x32_bf16(af, bk[j], acc[j], 0, 0, 0);
  }
  __syncthreads();                     // KT/VT dead after this point
  {
    const int colL = lane & 15, rb = frq * 4;
#pragma unroll
    for (int j = 0; j < 4; j++)
#pragma unroll
      for (int r = 0; r < 4; r++)
        KVT[w * 16 + rb + r][j * 16 + colL] = f2bf(acc[j][r]);
  }
  if (tid < 64) ksum_s[tid] = ksump[0][tid] + ksump[1][tid] + ksump[2][tid] + ksump[3][tid];
  __syncthreads();
  if (tid < 64) {
    const u16* qp = q + base + (long)tid * 512;
    float d = 0.f;
#pragma unroll
    for (int c8 = 0; c8 < 8; c8++) {
      uint4 u = ((const uint4*)qp)[c8];
      const u16* us = (const u16*)&u;
#pragma unroll
      for (int e = 0; e < 8; e++) d += bf2f(us[e]) * ksum_s[c8 * 8 + e];
    }
    dinv[tid] = 0.5f / (d + 1e-6f);
  }
  f32x4 acc2[4] = {};
#pragma unroll
  for (int ks = 0; ks < 2; ks++) {
    s16x8 aq, bk[4];
    aq = *(const s16x8*)(q + base + (long)(w * 16 + fr) * 512 + ks * 32 + fk);
#pragma unroll
    for (int j = 0; j < 4; j++)
      bk[j] = *(const s16x8*)&KVT[j * 16 + fr][ks * 32 + fk];
#pragma unroll
    for (int j = 0; j < 4; j++)
      acc2[j] = __builtin_amdgcn_mfma_f32_16x16x32_bf16(aq, bk[j], acc2[j], 0, 0, 0);
  }
  __syncthreads();   // dinv ready
  // stage contribution into dead KT area: Osm[64][66] u16
  u16* Osm = (u16*)&KT[0][0];
  const int colL = lane & 15, rb = frq * 4;
#pragma unroll
  for (int r = 0; r < 4; r++) {
    int nr = w * 16 + rb + r;
    float inv = dinv[nr];
#pragma unroll
    for (int j = 0; j < 4; j++)
      Osm[nr * 66 + j * 16 + colL] = f2bf(acc2[j][r] * inv);
  }
  __syncthreads();
#pragma unroll
  for (int rep = 0; rep < 2; rep++) {
    const int idx = rep * 256 + tid;
    const int nr = idx >> 3;
    const int c8 = (idx & 7) * 8;
    u16* dst = attc + base + (long)nr * 512 + c8;
    uint4 old = *(const uint4*)dst;
    uint4 cv = *(const uint4*)&Osm[nr * 66 + c8];
    const u16* op = (const u16*)&old;
    const u16* cp = (const u16*)&cv;
    union { u16 u[8]; uint4 v; } o;
#pragma unroll
    for (int e = 0; e < 8; e++) o.u[e] = f2bf(bf2f(op[e]) + bf2f(cp[e]));
    *(uint4*)dst = o.v;
  }
}

// ============================================================================
extern "C" void kernel_launch(void* const* d_in, const int* in_sizes, int n_in,
                              void* d_out, int out_size, void* d_ws, size_t ws_size,
                              hipStream_t stream) {
  const float* X    = (const float*)d_in[0];
  const float* Z    = (const float*)d_in[1];
  const float* n1   = (const float*)d_in[2];
  const float* n2   = (const float*)d_in[3];
  const float* n3   = (const float*)d_in[4];
  const float* nz   = (const float*)d_in[5];
  const float* a_wq = (const float*)d_in[6];
  const float* a_wk = (const float*)d_in[7];
  const float* a_wv = (const float*)d_in[8];
  const float* a_wo = (const float*)d_in[9];
  const float* c_wq = (const float*)d_in[10];
  const float* c_wk = (const float*)d_in[11];
  const float* c_wv = (const float*)d_in[12];
  const float* c_wo = (const float*)d_in[13];
  const float* f_w1 = (const float*)d_in[14];
  const float* f_w2 = (const float*)d_in[15];
  const float* f_w3 = (const float*)d_in[16];
  float* out = (float*)d_out;
  (void)ws_size; (void)in_sizes; (void)n_in; (void)out_size;

  char* p = (char*)d_ws;
  size_t off = 0;
  auto take = [&](size_t bytes) -> char* {
    char* r = p + off;
    off += (bytes + 255) & ~(size_t)255;
    return r;
  };
  // w_aq/w_ak/w_av contiguous => stacked [1536][512] QKV weight; w_ck/w_cv => [1024][512].
  u16* w_aq = (u16*)take(512 * 512 * 2);
  u16* w_ak = (u16*)take(512 * 512 * 2);
  u16* w_av = (u16*)take(512 * 512 * 2);
  u16* w_ao = (u16*)take(512 * 512 * 2);
  u16* w_cq = (u16*)take(512 * 512 * 2);
  u16* w_ck = (u16*)take(512 * 512 * 2);
  u16* w_cv = (u16*)take(512 * 512 * 2);
  u16* w_co = (u16*)take(512 * 512 * 2);
  u16* w_f1 = (u16*)take(2048 * 512 * 2);
  u16* w_f3 = (u16*)take(2048 * 512 * 2);
  u16* w_f2 = (u16*)take(512 * 2048 * 2);
  u16* xn   = (u16*)take((size_t)65536 * 512 * 2);   // normed input; attc aliases
  u16* hbuf = (u16*)take((size_t)65536 * 512 * 2);   // bf16 residual h
  u16* qbuf = (u16*)take((size_t)65536 * 512 * 2);   // q; FFN hidden chunk aliases
  // d_out as scratch (128 MiB): k | v  (dead before phase 3 writes out)
  u16* kbuf = (u16*)d_out;
  u16* vbuf = (u16*)d_out + (size_t)65536 * 512;
  u16* attc = xn;     // alias: normed input dead once projections done
  u16* tslot = qbuf;  // FFN: [16384][2048] bf16 chunk = 64 MiB

  dim3 b256(256);
  dim3 gQKV(12, 512);  // Ns=1536 fused qkv -> 6144 blocks
  dim3 gKV(8, 512);    // Ns=1024 fused kv  -> 4096 blocks
  dim3 gP(4, 512);     // N=512, M=65536    -> 2048 blocks
  dim3 gU(16, 128);    // N=2048, M=16384   -> 2048 blocks
  dim3 gD(4, 128);     // N=512, M=16384    -> 512 blocks

  // weight prep
  wprep<512, 512><<<64, b256, 0, stream>>>(a_wq, w_aq);
  wprep<512, 512><<<64, b256, 0, stream>>>(a_wk, w_ak);
  wprep<512, 512><<<64, b256, 0, stream>>>(a_wv, w_av);
  wprep<512, 512><<<64, b256, 0, stream>>>(a_wo, w_ao);
  wprep<512, 512><<<64, b256, 0, stream>>>(c_wq, w_cq);
  wprep<512, 512><<<64, b256, 0, stream>>>(c_wk, w_ck);
  wprep<512, 512><<<64, b256, 0, stream>>>(c_wv, w_cv);
  wprep<512, 512><<<64, b256, 0, stream>>>(c_wo, w_co);
  wprep<512, 2048><<<256, b256, 0, stream>>>(f_w1, w_f1);
  wprep<512, 2048><<<256, b256, 0, stream>>>(f_w3, w_f3);
  wprep<2048, 512><<<256, b256, 0, stream>>>(f_w2, w_f2);

  // ---------------- Phase 1: h = X + SelfAtt(norm1(X)) ----------------------
  rmsnorm_f32<<<16384, b256, 0, stream>>>(X, n1, xn);
  gemm128<512, EPI_QKV><<<gQKV, b256, 0, stream>>>(xn, w_aq, qbuf, kbuf, vbuf, nullptr, 1536);
  att_mode1<<<2048, b256, 0, stream>>>(qbuf, kbuf, vbuf, attc);
  att_mode2<<<8192, b256, 0, stream>>>(qbuf, kbuf, vbuf, attc);
  gemm128<512, EPI_RESX><<<gP, b256, 0, stream>>>(attc, w_ao, hbuf, nullptr, nullptr, X, 512);

  // ---------------- Phase 2: h += CrossAtt(norm3(h), normz(Z)) --------------
  rmsnorm_bf16<<<16384, b256, 0, stream>>>(hbuf, n3, xn);
  gemm128<512, EPI_PHI><<<gP, b256, 0, stream>>>(xn, w_cq, qbuf, nullptr, nullptr, nullptr, 512);
  rmsnorm_f32<<<16384, b256, 0, stream>>>(Z, nz, xn);
  gemm128<512, EPI_KV><<<gKV, b256, 0, stream>>>(xn, w_ck, kbuf, vbuf, nullptr, nullptr, 1024);
  att_mode1<<<2048, b256, 0, stream>>>(qbuf, kbuf, vbuf, attc);
  att_mode2<<<8192, b256, 0, stream>>>(qbuf, kbuf, vbuf, attc);
  gemm128<512, EPI_RESH><<<gP, b256, 0, stream>>>(attc, w_co, hbuf, nullptr, nullptr, hbuf, 512);

  // ---------------- Phase 3: out = h + SwiGLU(norm2(h)) ---------------------
  rmsnorm_bf16<<<16384, b256, 0, stream>>>(hbuf, n2, xn);
  const int CH = 16384;
  for (int c = 0; c < 4; c++) {
    const size_t ro = (size_t)c * CH * 512;
    gemm128<512, EPI_BF16><<<gU, b256, 0, stream>>>(xn + ro, w_f1, tslot, nullptr, nullptr, nullptr, 2048);
    gemm128<512, EPI_SILUMUL><<<gU, b256, 0, stream>>>(xn + ro, w_f3, tslot, nullptr, nullptr, tslot, 2048);
    gemm128<2048, EPI_OUTF><<<gD, b256, 0, stream>>>(tslot, w_f2, out + ro, nullptr, nullptr, hbuf + ro, 512);
  }
}